// Round 2
// baseline (395.050 us; speedup 1.0000x reference)
//
#include <hip/hip_runtime.h>
#include <cstdint>

#define L_ 4096
#define NC_ 512
#define CD_ 256
#define H_ 8
#define D_ 128
#define B_ 4
#define SCALE 0.08838834764831845f
#define TAU 3.0e-3f

typedef _Float16 f16x8 __attribute__((ext_vector_type(8)));
typedef _Float16 f16x4 __attribute__((ext_vector_type(4)));
typedef float f32x16 __attribute__((ext_vector_type(16)));
typedef float f32x4 __attribute__((ext_vector_type(4)));

// ---------------------------------------------------------------------------
// Kernel A: K16f = fp16 K in MFMA-A-fragment-major layout [(h,nt,ds)][lane][8]
//           K32  = fp32 K [h][n][d] (for exact repair)
//           V    = fp32 V [h][n][d] (for gather)
// frag element j of (nt,ds,lane) <-> K[n = nt*32 + (lane&31)][d = ds*16 + (lane>>5)*8 + j]
// ---------------------------------------------------------------------------
__global__ __launch_bounds__(256) void kv_pre(
    const float* __restrict__ codes, const float* __restrict__ Wk,
    const float* __restrict__ Wv, _Float16* __restrict__ K16f,
    float* __restrict__ K32, float* __restrict__ V)
{
    __shared__ float clds[8][256];   // 8 KB
    const int t = threadIdx.x, h = blockIdx.y, n0 = blockIdx.x * 8;
    {
        const float4* cs = (const float4*)(codes + (size_t)n0 * CD_);
        float4* cd = (float4*)&clds[0][0];
        cd[t] = cs[t]; cd[t + 256] = cs[t + 256];
    }
    __syncthreads();
    const int nl = t >> 5, dq = t & 31, d0 = dq * 4, n = n0 + nl;
    float ak0=0,ak1=0,ak2=0,ak3=0, av0=0,av1=0,av2=0,av3=0;
    const float4* wk4 = (const float4*)Wk;
    const float4* wv4 = (const float4*)Wv;
    for (int c = 0; c < CD_; c += 4) {
        float4 cv = *(const float4*)&clds[nl][c];
        #pragma unroll
        for (int u = 0; u < 4; ++u) {
            float cu = (u==0)?cv.x:(u==1)?cv.y:(u==2)?cv.z:cv.w;
            float4 wk = wk4[((size_t)(c+u)*H_ + h)*32 + dq];
            float4 wv = wv4[((size_t)(c+u)*H_ + h)*32 + dq];
            ak0 = fmaf(cu, wk.x, ak0); ak1 = fmaf(cu, wk.y, ak1);
            ak2 = fmaf(cu, wk.z, ak2); ak3 = fmaf(cu, wk.w, ak3);
            av0 = fmaf(cu, wv.x, av0); av1 = fmaf(cu, wv.y, av1);
            av2 = fmaf(cu, wv.z, av2); av3 = fmaf(cu, wv.w, av3);
        }
    }
    const size_t r32 = ((size_t)(h*NC_ + n))*D_ + d0;
    float4 sk; sk.x=ak0; sk.y=ak1; sk.z=ak2; sk.w=ak3;
    float4 sv; sv.x=av0; sv.y=av1; sv.z=av2; sv.w=av3;
    *(float4*)(K32 + r32) = sk;
    *(float4*)(V   + r32) = sv;
    // fp16 fragment-major write (8B store)
    f16x4 hk; hk[0]=(_Float16)ak0; hk[1]=(_Float16)ak1; hk[2]=(_Float16)ak2; hk[3]=(_Float16)ak3;
    const size_t a16 = ((size_t)((h*16 + (n>>5))*8 + (d0>>4))*64
                        + ((n&31) + ((d0>>3)&1)*32))*8 + (d0&7);
    *(f16x4*)(K16f + a16) = hk;
}

// ---------------------------------------------------------------------------
// Kernel B: fused logits (fp16 MFMA) + top-3 track + two-tier exact repair +
//           V gather. Barrier-free: each wave independently owns 64 l's.
// ---------------------------------------------------------------------------
__global__ __launch_bounds__(256, 2) void attn_main(
    const float* __restrict__ x, const _Float16* __restrict__ K16f,
    const float* __restrict__ K32, const float* __restrict__ V,
    float* __restrict__ out, float* __restrict__ idxf)
{
    __shared__ float qbuf[4][128];   // per-wave repair q staging
    const int t = threadIdx.x;
    const int wid = t >> 6, lane = t & 63;
    // XCD-aware bijective swizzle (512 blocks, 8 XCDs)
    const int bid = blockIdx.x;
    const int swz = ((bid & 7) << 6) | (bid >> 3);
    const int lx = swz & 15, h = (swz >> 4) & 7, b = swz >> 7;
    const int l0w = lx * 256 + wid * 64;

    const float* xb = x + ((size_t)(b*1024 + h*128)) * L_;
    const int colL = lane & 31;
    const int hi = lane >> 5;
    const int dbase = hi * 8;

    // ---- q fragments in registers: qf[s][ds][j] = scale*x[d=ds*16+hi*8+j][l0w+s*32+colL]
    f16x8 qf[2][8];
    #pragma unroll
    for (int s = 0; s < 2; ++s) {
        const int lq = l0w + s*32 + colL;
        #pragma unroll
        for (int ds = 0; ds < 8; ++ds) {
            const float* px = xb + (size_t)(ds*16 + dbase)*L_ + lq;
            f16x8 tmp;
            #pragma unroll
            for (int j = 0; j < 8; ++j) tmp[j] = (_Float16)(SCALE * px[(size_t)j*L_]);
            qf[s][ds] = tmp;
        }
    }

    const _Float16* kh = K16f + ((size_t)h << 16);   // 65536 halfs per head

    float v1[2], v2[2], v3[2]; int i1[2], i2[2];
    #pragma unroll
    for (int s = 0; s < 2; ++s) { v1[s]=v2[s]=v3[s]=-INFINITY; i1[s]=0; i2[s]=0; }
    const int laneN4 = hi * 4;

    // double-buffered K-fragment prefetch (coalesced 1KB/instr, L2-resident)
    f16x8 kb[2][8];
    #pragma unroll
    for (int ds = 0; ds < 8; ++ds)
        kb[0][ds] = *(const f16x8*)(kh + ((size_t)(ds)*64 + lane)*8);

    #pragma unroll
    for (int nt = 0; nt < 16; ++nt) {
        const int cur = nt & 1, nxt = cur ^ 1;
        if (nt < 15) {
            #pragma unroll
            for (int ds = 0; ds < 8; ++ds)
                kb[nxt][ds] = *(const f16x8*)(kh + ((size_t)((nt+1)*8 + ds)*64 + lane)*8);
        }
        f32x16 acc0, acc1;
        #pragma unroll
        for (int r = 0; r < 16; ++r) { acc0[r] = 0.f; acc1[r] = 0.f; }
        #pragma unroll
        for (int ds = 0; ds < 8; ++ds) {
            acc0 = __builtin_amdgcn_mfma_f32_32x32x16_f16(kb[cur][ds], qf[0][ds], acc0, 0, 0, 0);
            acc1 = __builtin_amdgcn_mfma_f32_32x32x16_f16(kb[cur][ds], qf[1][ds], acc1, 0, 0, 0);
        }
        // top-3 values + top-2 indices, per strip
        #pragma unroll
        for (int s = 0; s < 2; ++s) {
            #pragma unroll
            for (int r = 0; r < 16; ++r) {
                float v = s ? acc1[r] : acc0[r];
                int n = nt*32 + (r&3) + ((r>>2)<<3) + laneN4;
                bool gt1 = v > v1[s];
                bool gt2 = v > v2[s];
                i2[s] = gt1 ? i1[s] : (gt2 ? n : i2[s]);
                i1[s] = gt1 ? n     : i1[s];
                v3[s] = fmaxf(v3[s], fminf(v2[s], v));
                v2[s] = fmaxf(v2[s], fminf(v1[s], v));
                v1[s] = fmaxf(v1[s], v);
            }
        }
    }

    // ---- merge the two half-row sets (lane ^ 32) per strip
    float m1[2], m2v[2], m3v[2]; int mi1[2], mi2[2];
    #pragma unroll
    for (int s = 0; s < 2; ++s) {
        float ov1 = __shfl_xor(v1[s], 32);
        float ov2 = __shfl_xor(v2[s], 32);
        float ov3 = __shfl_xor(v3[s], 32);
        int oi1 = __shfl_xor(i1[s], 32);
        int oi2 = __shfl_xor(i2[s], 32);
        bool sw = (ov1 > v1[s]) || (ov1 == v1[s] && oi1 < i1[s]);
        float a1 = sw ? ov1 : v1[s];  int ai1 = sw ? oi1 : i1[s];
        float b1 = sw ? v1[s] : ov1;  int bi1 = sw ? i1[s] : oi1;
        float a2 = sw ? ov2 : v2[s];  int ai2 = sw ? oi2 : i2[s];
        float b2 = sw ? v2[s] : ov2;
        float a3 = sw ? ov3 : v3[s];
        bool sec = (b1 > a2) || (b1 == a2 && bi1 < ai2);
        m1[s] = a1; mi1[s] = ai1;
        m2v[s] = sec ? b1 : a2;  mi2[s] = sec ? bi1 : ai2;
        m3v[s] = sec ? fmaxf(a2, b2) : fmaxf(a3, b1);
    }
    const float V1 = hi ? m1[1]  : m1[0];
    const float V2 = hi ? m2v[1] : m2v[0];
    const float V3 = hi ? m3v[1] : m3v[0];
    const int   I1 = hi ? mi1[1] : mi1[0];
    const int   I2 = hi ? mi2[1] : mi2[0];
    int idx = I1;
    const int myl = l0w + lane;   // this lane owns l = l0w + lane

    const bool cheap = (V1 - V2 < TAU) && (V1 - V3 >= TAU);
    const bool full  = (V1 - V3 < TAU);

    // ---- cheap repair: exact fp32 dots for the two candidates only
    unsigned long long mc = __ballot(cheap);
    while (mc) {
        int src = (int)__builtin_ctzll(mc); mc &= mc - 1;
        int rl = l0w + src;
        int ra = __shfl(I1, src);
        int rb = __shfl(I2, src);
        int n = hi ? rb : ra;
        f32x4 kk = *(const f32x4*)(K32 + ((size_t)(h*NC_ + n))*D_ + colL*4);
        int dd = colL * 4;
        float q0 = SCALE * xb[(size_t)(dd+0)*L_ + rl];
        float q1 = SCALE * xb[(size_t)(dd+1)*L_ + rl];
        float q2 = SCALE * xb[(size_t)(dd+2)*L_ + rl];
        float q3 = SCALE * xb[(size_t)(dd+3)*L_ + rl];
        float p = q0 * kk[0];
        p = fmaf(q1, kk[1], p); p = fmaf(q2, kk[2], p); p = fmaf(q3, kk[3], p);
        #pragma unroll
        for (int m = 1; m < 32; m <<= 1) p += __shfl_xor(p, m);
        float va = __shfl(p, 0);
        float vb = __shfl(p, 32);
        bool takeB = (vb > va) || (vb == va && rb < ra);
        int win = takeB ? rb : ra;
        if (lane == src) idx = win;
    }

    // ---- full repair (rare): exact fp32 re-scan of all 512 codes
    unsigned long long mf = __ballot(full);
    float* qb = qbuf[wid];
    while (mf) {
        int src = (int)__builtin_ctzll(mf); mf &= mf - 1;
        int rl = l0w + src;
        qb[lane]      = SCALE * xb[(size_t)lane*L_ + rl];
        qb[lane + 64] = SCALE * xb[(size_t)(lane+64)*L_ + rl];
        __builtin_amdgcn_wave_barrier();
        asm volatile("s_waitcnt lgkmcnt(0)" ::: "memory");
        float accs[8];
        #pragma unroll
        for (int u = 0; u < 8; ++u) accs[u] = 0.f;
        const float* kr = K32 + ((size_t)(h*NC_ + lane))*D_;
        for (int d4 = 0; d4 < 32; ++d4) {
            float qd0 = qb[d4*4+0], qd1 = qb[d4*4+1], qd2 = qb[d4*4+2], qd3 = qb[d4*4+3];
            #pragma unroll
            for (int u = 0; u < 8; ++u) {
                f32x4 kk = *(const f32x4*)(kr + (size_t)u*64*D_ + d4*4);
                accs[u] = fmaf(qd0, kk[0], accs[u]);
                accs[u] = fmaf(qd1, kk[1], accs[u]);
                accs[u] = fmaf(qd2, kk[2], accs[u]);
                accs[u] = fmaf(qd3, kk[3], accs[u]);
            }
        }
        float bv = -INFINITY; int bn = 0;
        #pragma unroll
        for (int u = 0; u < 8; ++u) {
            if (accs[u] > bv) { bv = accs[u]; bn = lane + (u << 6); }
        }
        #pragma unroll
        for (int m = 1; m < 64; m <<= 1) {
            float ov = __shfl_xor(bv, m);
            int on = __shfl_xor(bn, m);
            if (ov > bv || (ov == bv && on < bn)) { bv = ov; bn = on; }
        }
        if (lane == src) idx = bn;
        __builtin_amdgcn_wave_barrier();
    }

    // ---- outputs: idx (as float) + fused V gather
    idxf[((size_t)(b*H_ + h))*L_ + myl] = (float)idx;
    const f32x4* vrow = (const f32x4*)(V + ((size_t)(h*NC_ + idx))*D_);
    float* ob = out + ((size_t)(b*1024 + h*128))*L_ + myl;
    #pragma unroll
    for (int p = 0; p < 32; ++p) {
        f32x4 vv = vrow[p];
        ob[(size_t)(p*4+0)*L_] = vv[0];
        ob[(size_t)(p*4+1)*L_] = vv[1];
        ob[(size_t)(p*4+2)*L_] = vv[2];
        ob[(size_t)(p*4+3)*L_] = vv[3];
    }
}

extern "C" void kernel_launch(void* const* d_in, const int* in_sizes, int n_in,
                              void* d_out, int out_size, void* d_ws, size_t ws_size,
                              hipStream_t stream)
{
    const float* x     = (const float*)d_in[0];
    const float* codes = (const float*)d_in[1];
    const float* Wk    = (const float*)d_in[2];
    const float* Wv    = (const float*)d_in[3];

    float* out  = (float*)d_out;
    float* idxf = out + (size_t)B_ * H_ * D_ * L_;

    _Float16* K16f = (_Float16*)d_ws;                        // 1 MB
    float*    K32  = (float*)((char*)d_ws + (1u << 20));     // 2 MB
    float*    Vf   = (float*)((char*)d_ws + (3u << 20));     // 2 MB

    kv_pre<<<dim3(64, 8), 256, 0, stream>>>(codes, Wk, Wv, K16f, K32, Vf);
    attn_main<<<dim3(512), 256, 0, stream>>>(x, K16f, K32, Vf, out, idxf);
}

// Round 3
// 197.604 us; speedup vs baseline: 1.9992x; 1.9992x over previous
//
#include <hip/hip_runtime.h>
#include <cstdint>

#define L_ 4096
#define NC_ 512
#define CD_ 256
#define H_ 8
#define D_ 128
#define B_ 4
#define SCALE 0.08838834764831845f
#define TAU 3.0e-3f

typedef _Float16 f16x8 __attribute__((ext_vector_type(8)));
typedef _Float16 f16x4 __attribute__((ext_vector_type(4)));
typedef float f32x16 __attribute__((ext_vector_type(16)));
typedef float f32x4 __attribute__((ext_vector_type(4)));

// ---------------------------------------------------------------------------
// Kernel A (verbatim from round 2 — verified): K16f fp16 fragment-major,
// K32/V fp32 row-major.
// ---------------------------------------------------------------------------
__global__ __launch_bounds__(256) void kv_pre(
    const float* __restrict__ codes, const float* __restrict__ Wk,
    const float* __restrict__ Wv, _Float16* __restrict__ K16f,
    float* __restrict__ K32, float* __restrict__ V)
{
    __shared__ float clds[8][256];
    const int t = threadIdx.x, h = blockIdx.y, n0 = blockIdx.x * 8;
    {
        const float4* cs = (const float4*)(codes + (size_t)n0 * CD_);
        float4* cd = (float4*)&clds[0][0];
        cd[t] = cs[t]; cd[t + 256] = cs[t + 256];
    }
    __syncthreads();
    const int nl = t >> 5, dq = t & 31, d0 = dq * 4, n = n0 + nl;
    float ak0=0,ak1=0,ak2=0,ak3=0, av0=0,av1=0,av2=0,av3=0;
    const float4* wk4 = (const float4*)Wk;
    const float4* wv4 = (const float4*)Wv;
    for (int c = 0; c < CD_; c += 4) {
        float4 cv = *(const float4*)&clds[nl][c];
        #pragma unroll
        for (int u = 0; u < 4; ++u) {
            float cu = (u==0)?cv.x:(u==1)?cv.y:(u==2)?cv.z:cv.w;
            float4 wk = wk4[((size_t)(c+u)*H_ + h)*32 + dq];
            float4 wv = wv4[((size_t)(c+u)*H_ + h)*32 + dq];
            ak0 = fmaf(cu, wk.x, ak0); ak1 = fmaf(cu, wk.y, ak1);
            ak2 = fmaf(cu, wk.z, ak2); ak3 = fmaf(cu, wk.w, ak3);
            av0 = fmaf(cu, wv.x, av0); av1 = fmaf(cu, wv.y, av1);
            av2 = fmaf(cu, wv.z, av2); av3 = fmaf(cu, wv.w, av3);
        }
    }
    const size_t r32 = ((size_t)(h*NC_ + n))*D_ + d0;
    float4 sk; sk.x=ak0; sk.y=ak1; sk.z=ak2; sk.w=ak3;
    float4 sv; sv.x=av0; sv.y=av1; sv.z=av2; sv.w=av3;
    *(float4*)(K32 + r32) = sk;
    *(float4*)(V   + r32) = sv;
    f16x4 hk; hk[0]=(_Float16)ak0; hk[1]=(_Float16)ak1; hk[2]=(_Float16)ak2; hk[3]=(_Float16)ak3;
    const size_t a16 = ((size_t)((h*16 + (n>>5))*8 + (d0>>4))*64
                        + ((n&31) + ((d0>>3)&1)*32))*8 + (d0&7);
    *(f16x4*)(K16f + a16) = hk;
}

// ---------------------------------------------------------------------------
// Kernel B: static (spill-free) double-buffered fp16 MFMA logits + top-2
// track + exact fp32 full-repair for near-ties + fused V gather.
// ---------------------------------------------------------------------------

#define LOADK(BANK, TILE)                                                      \
  _Pragma("unroll")                                                            \
  for (int ds = 0; ds < 8; ++ds)                                               \
    BANK[ds] = *(const f16x8*)(kh + ((size_t)((TILE)*8 + ds)*64 + lane)*8);

#define PROCESS(BANK, TILE)                                                    \
  {                                                                            \
    f32x16 acc0, acc1;                                                         \
    _Pragma("unroll")                                                          \
    for (int r = 0; r < 16; ++r) { acc0[r] = 0.f; acc1[r] = 0.f; }             \
    _Pragma("unroll")                                                          \
    for (int ds = 0; ds < 8; ++ds) {                                           \
      acc0 = __builtin_amdgcn_mfma_f32_32x32x16_f16(BANK[ds], qf0[ds], acc0, 0, 0, 0); \
      acc1 = __builtin_amdgcn_mfma_f32_32x32x16_f16(BANK[ds], qf1[ds], acc1, 0, 0, 0); \
    }                                                                          \
    const int nb = (TILE)*32 + laneN4;                                         \
    _Pragma("unroll")                                                          \
    for (int r = 0; r < 16; ++r) {                                             \
      const int n = nb + (r & 3) + ((r >> 2) << 3);                            \
      float v = acc0[r];                                                       \
      bool g = v > v1_0;                                                       \
      v2_0 = fmaxf(v2_0, fminf(v1_0, v));                                      \
      v1_0 = fmaxf(v1_0, v);                                                   \
      i1_0 = g ? n : i1_0;                                                     \
      v = acc1[r];                                                             \
      g = v > v1_1;                                                            \
      v2_1 = fmaxf(v2_1, fminf(v1_1, v));                                      \
      v1_1 = fmaxf(v1_1, v);                                                   \
      i1_1 = g ? n : i1_1;                                                     \
    }                                                                          \
  }

__global__ __launch_bounds__(256, 2) void attn_main(
    const float* __restrict__ x, const _Float16* __restrict__ K16f,
    const float* __restrict__ K32, const float* __restrict__ V,
    float* __restrict__ out, float* __restrict__ idxf)
{
    __shared__ float qbuf[4][128];
    const int t = threadIdx.x;
    const int wid = t >> 6, lane = t & 63;
    const int bid = blockIdx.x;
    const int swz = ((bid & 7) << 6) | (bid >> 3);   // XCD-aware bijective (512 % 8 == 0)
    const int lx = swz & 15, h = (swz >> 4) & 7, b = swz >> 7;
    const int l0w = lx * 256 + wid * 64;

    const float* xb = x + ((size_t)(b*1024 + h*128)) * L_;
    const int colL = lane & 31;
    const int hi = lane >> 5;
    const int dbase = hi * 8;
    const int laneN4 = hi * 4;

    // ---- q fragments (static arrays, verified layout from round 2)
    f16x8 qf0[8], qf1[8];
    #pragma unroll
    for (int ds = 0; ds < 8; ++ds) {
        const float* px = xb + (size_t)(ds*16 + dbase)*L_ + l0w + colL;
        f16x8 t0, t1;
        #pragma unroll
        for (int j = 0; j < 8; ++j) t0[j] = (_Float16)(SCALE * px[(size_t)j*L_]);
        #pragma unroll
        for (int j = 0; j < 8; ++j) t1[j] = (_Float16)(SCALE * px[(size_t)j*L_ + 32]);
        qf0[ds] = t0;
        qf1[ds] = t1;
    }

    const _Float16* kh = K16f + ((size_t)h << 16);

    float v1_0 = -INFINITY, v2_0 = -INFINITY;
    float v1_1 = -INFINITY, v2_1 = -INFINITY;
    int i1_0 = 0, i1_1 = 0;

    // ---- statically double-buffered K-fragment loop (16 tiles, 2 per iter)
    f16x8 kA[8], kB[8];
    LOADK(kA, 0)
    for (int t2 = 0; t2 < 8; ++t2) {
        LOADK(kB, 2*t2 + 1)
        PROCESS(kA, 2*t2)
        if (t2 < 7) { LOADK(kA, 2*t2 + 2) }
        PROCESS(kB, 2*t2 + 1)
    }

    // ---- merge lane^32 halves per strip (values-only second place)
    float mV1[2], mV2[2]; int mI1[2];
    {
        float a1 = v1_0, a2 = v2_0; int ai = i1_0;
        float o1 = __shfl_xor(a1, 32), o2 = __shfl_xor(a2, 32);
        int oi = __shfl_xor(ai, 32);
        bool sw = (o1 > a1) || (o1 == a1 && oi < ai);
        mV1[0] = sw ? o1 : a1; mI1[0] = sw ? oi : ai;
        mV2[0] = fmaxf(fminf(a1, o1), fmaxf(a2, o2));
    }
    {
        float a1 = v1_1, a2 = v2_1; int ai = i1_1;
        float o1 = __shfl_xor(a1, 32), o2 = __shfl_xor(a2, 32);
        int oi = __shfl_xor(ai, 32);
        bool sw = (o1 > a1) || (o1 == a1 && oi < ai);
        mV1[1] = sw ? o1 : a1; mI1[1] = sw ? oi : ai;
        mV2[1] = fmaxf(fminf(a1, o1), fmaxf(a2, o2));
    }
    const float V1 = hi ? mV1[1] : mV1[0];
    const float V2 = hi ? mV2[1] : mV2[0];
    int idx = hi ? mI1[1] : mI1[0];
    const int myl = l0w + lane;

    // ---- exact fp32 full repair for near-ties (row-serialized within wave)
    unsigned long long mf = __ballot(V1 - V2 < TAU);
    float* qb = qbuf[wid];
    while (mf) {
        int src = (int)__builtin_ctzll(mf); mf &= mf - 1;
        int rl = l0w + src;
        qb[lane]      = SCALE * xb[(size_t)lane*L_ + rl];
        qb[lane + 64] = SCALE * xb[(size_t)(lane+64)*L_ + rl];
        __builtin_amdgcn_wave_barrier();
        asm volatile("s_waitcnt lgkmcnt(0)" ::: "memory");
        float accs[8];
        #pragma unroll
        for (int u = 0; u < 8; ++u) accs[u] = 0.f;
        const float* kr = K32 + ((size_t)(h*NC_ + lane))*D_;
        for (int d4 = 0; d4 < 32; ++d4) {
            float qd0 = qb[d4*4+0], qd1 = qb[d4*4+1], qd2 = qb[d4*4+2], qd3 = qb[d4*4+3];
            #pragma unroll
            for (int u = 0; u < 8; ++u) {
                f32x4 kk = *(const f32x4*)(kr + (size_t)u*64*D_ + d4*4);
                accs[u] = fmaf(qd0, kk[0], accs[u]);
                accs[u] = fmaf(qd1, kk[1], accs[u]);
                accs[u] = fmaf(qd2, kk[2], accs[u]);
                accs[u] = fmaf(qd3, kk[3], accs[u]);
            }
        }
        float bv = -INFINITY; int bn = 0;
        #pragma unroll
        for (int u = 0; u < 8; ++u) {
            if (accs[u] > bv) { bv = accs[u]; bn = lane + (u << 6); }
        }
        #pragma unroll
        for (int m = 1; m < 64; m <<= 1) {
            float ov = __shfl_xor(bv, m);
            int on = __shfl_xor(bn, m);
            if (ov > bv || (ov == bv && on < bn)) { bv = ov; bn = on; }
        }
        if (lane == src) idx = bn;
        __builtin_amdgcn_wave_barrier();
    }

    // ---- outputs: idx (as float) + fused V gather
    idxf[((size_t)(b*H_ + h))*L_ + myl] = (float)idx;
    const f32x4* vrow = (const f32x4*)(V + ((size_t)(h*NC_ + idx))*D_);
    float* ob = out + ((size_t)(b*1024 + h*128))*L_ + myl;
    #pragma unroll
    for (int p = 0; p < 32; ++p) {
        f32x4 vv = vrow[p];
        ob[(size_t)(p*4+0)*L_] = vv[0];
        ob[(size_t)(p*4+1)*L_] = vv[1];
        ob[(size_t)(p*4+2)*L_] = vv[2];
        ob[(size_t)(p*4+3)*L_] = vv[3];
    }
}

extern "C" void kernel_launch(void* const* d_in, const int* in_sizes, int n_in,
                              void* d_out, int out_size, void* d_ws, size_t ws_size,
                              hipStream_t stream)
{
    const float* x     = (const float*)d_in[0];
    const float* codes = (const float*)d_in[1];
    const float* Wk    = (const float*)d_in[2];
    const float* Wv    = (const float*)d_in[3];

    float* out  = (float*)d_out;
    float* idxf = out + (size_t)B_ * H_ * D_ * L_;

    _Float16* K16f = (_Float16*)d_ws;                        // 1 MB
    float*    K32  = (float*)((char*)d_ws + (1u << 20));     // 2 MB
    float*    Vf   = (float*)((char*)d_ws + (3u << 20));     // 2 MB

    kv_pre<<<dim3(64, 8), 256, 0, stream>>>(codes, Wk, Wv, K16f, K32, Vf);
    attn_main<<<dim3(512), 256, 0, stream>>>(x, K16f, K32, Vf, out, idxf);
}

// Round 4
// 161.836 us; speedup vs baseline: 2.4411x; 1.2210x over previous
//
#include <hip/hip_runtime.h>
#include <cstdint>

#define L_ 4096
#define NC_ 512
#define CD_ 256
#define H_ 8
#define D_ 128
#define B_ 4
#define SCALE 0.08838834764831845f
#define TAU 3.0e-3f

typedef _Float16 f16x8 __attribute__((ext_vector_type(8)));
typedef _Float16 f16x4 __attribute__((ext_vector_type(4)));
typedef float f32x16 __attribute__((ext_vector_type(16)));
typedef float f32x4 __attribute__((ext_vector_type(4)));

// ---------------------------------------------------------------------------
// Kernel A (verbatim, verified): K16f fp16 fragment-major, K32/V fp32 row-major.
// ---------------------------------------------------------------------------
__global__ __launch_bounds__(256) void kv_pre(
    const float* __restrict__ codes, const float* __restrict__ Wk,
    const float* __restrict__ Wv, _Float16* __restrict__ K16f,
    float* __restrict__ K32, float* __restrict__ V)
{
    __shared__ float clds[8][256];
    const int t = threadIdx.x, h = blockIdx.y, n0 = blockIdx.x * 8;
    {
        const float4* cs = (const float4*)(codes + (size_t)n0 * CD_);
        float4* cd = (float4*)&clds[0][0];
        cd[t] = cs[t]; cd[t + 256] = cs[t + 256];
    }
    __syncthreads();
    const int nl = t >> 5, dq = t & 31, d0 = dq * 4, n = n0 + nl;
    float ak0=0,ak1=0,ak2=0,ak3=0, av0=0,av1=0,av2=0,av3=0;
    const float4* wk4 = (const float4*)Wk;
    const float4* wv4 = (const float4*)Wv;
    for (int c = 0; c < CD_; c += 4) {
        float4 cv = *(const float4*)&clds[nl][c];
        #pragma unroll
        for (int u = 0; u < 4; ++u) {
            float cu = (u==0)?cv.x:(u==1)?cv.y:(u==2)?cv.z:cv.w;
            float4 wk = wk4[((size_t)(c+u)*H_ + h)*32 + dq];
            float4 wv = wv4[((size_t)(c+u)*H_ + h)*32 + dq];
            ak0 = fmaf(cu, wk.x, ak0); ak1 = fmaf(cu, wk.y, ak1);
            ak2 = fmaf(cu, wk.z, ak2); ak3 = fmaf(cu, wk.w, ak3);
            av0 = fmaf(cu, wv.x, av0); av1 = fmaf(cu, wv.y, av1);
            av2 = fmaf(cu, wv.z, av2); av3 = fmaf(cu, wv.w, av3);
        }
    }
    const size_t r32 = ((size_t)(h*NC_ + n))*D_ + d0;
    float4 sk; sk.x=ak0; sk.y=ak1; sk.z=ak2; sk.w=ak3;
    float4 sv; sv.x=av0; sv.y=av1; sv.z=av2; sv.w=av3;
    *(float4*)(K32 + r32) = sk;
    *(float4*)(V   + r32) = sv;
    f16x4 hk; hk[0]=(_Float16)ak0; hk[1]=(_Float16)ak1; hk[2]=(_Float16)ak2; hk[3]=(_Float16)ak3;
    const size_t a16 = ((size_t)((h*16 + (n>>5))*8 + (d0>>4))*64
                        + ((n&31) + ((d0>>3)&1)*32))*8 + (d0&7);
    *(f16x4*)(K16f + a16) = hk;
}

// ---------------------------------------------------------------------------
// Kernel B: 4-wave block, 32 l's per wave, LDS-staged K tiles via
// global_load_lds(16B), double-buffered; fp16 MFMA logits + top-2 + exact
// fp32 repair + fused V gather.
// ---------------------------------------------------------------------------

#define GLD_LDS16(GP, LP)                                                      \
  __builtin_amdgcn_global_load_lds(                                            \
      (const __attribute__((address_space(1))) void*)(GP),                     \
      (__attribute__((address_space(3))) void*)(LP), 16, 0, 0)

__global__ __launch_bounds__(256, 4) void attn_main(
    const float* __restrict__ x, const _Float16* __restrict__ K16f,
    const float* __restrict__ K32, const float* __restrict__ V,
    float* __restrict__ out, float* __restrict__ idxf)
{
    __shared__ _Float16 kbuf[2][4096];   // 2 x 8KB K tiles (fragment-major)
    __shared__ float qbuf[4][128];       // per-wave repair staging
    const int t = threadIdx.x;
    const int wid = t >> 6, lane = t & 63;
    const int bid = blockIdx.x;
    const int h  = bid & 7;              // head-per-XCD affinity
    const int rr_ = bid >> 3;
    const int lx = rr_ & 31, b = rr_ >> 5;
    const int l0w = lx * 128 + wid * 32;

    const float* xb = x + ((size_t)(b*1024 + h*128)) * L_;
    const int colL = lane & 31;
    const int hi = lane >> 5;
    const int dbase = hi * 8;
    const int laneN4 = hi * 4;

    const _Float16* kh = K16f + ((size_t)h << 16);   // 65536 halfs per head

    // ---- stage tile 0 early (hides under q HBM loads)
    {
        const _Float16* src = kh;
        GLD_LDS16(src + (size_t)(wid*64 + lane)*8,        &kbuf[0][(size_t)(wid*64)*8]);
        GLD_LDS16(src + (size_t)(256 + wid*64 + lane)*8,  &kbuf[0][(size_t)(256 + wid*64)*8]);
    }

    // ---- q: bulk-issue 64 f32 loads, then convert to 8 fp16x8 fragments
    float qraw[64];
    #pragma unroll
    for (int ds = 0; ds < 8; ++ds) {
        const float* px = xb + (size_t)(ds*16 + dbase)*L_ + l0w + colL;
        #pragma unroll
        for (int j = 0; j < 8; ++j)
            qraw[ds*8 + j] = px[(size_t)j*L_];
    }
    f16x8 qf[8];
    #pragma unroll
    for (int ds = 0; ds < 8; ++ds) {
        f16x8 tmp;
        #pragma unroll
        for (int j = 0; j < 8; ++j) tmp[j] = (_Float16)(SCALE * qraw[ds*8 + j]);
        qf[ds] = tmp;
    }

    float v1 = -INFINITY, v2 = -INFINITY;
    int i1 = 0;

    __syncthreads();   // tile 0 staged (vmcnt drained by syncthreads)

    for (int nt = 0; nt < 16; ++nt) {
        const int bf = nt & 1;
        if (nt < 15) {   // stage next tile into the other buffer
            const _Float16* src = kh + (size_t)(nt+1)*4096;
            GLD_LDS16(src + (size_t)(wid*64 + lane)*8,       &kbuf[bf^1][(size_t)(wid*64)*8]);
            GLD_LDS16(src + (size_t)(256 + wid*64 + lane)*8, &kbuf[bf^1][(size_t)(256 + wid*64)*8]);
        }
        f32x16 acc;
        #pragma unroll
        for (int r = 0; r < 16; ++r) acc[r] = 0.f;
        #pragma unroll
        for (int ds = 0; ds < 8; ++ds) {
            f16x8 kf = *(const f16x8*)&kbuf[bf][(size_t)(ds*64 + lane)*8];
            acc = __builtin_amdgcn_mfma_f32_32x32x16_f16(kf, qf[ds], acc, 0, 0, 0);
        }
        const int nb = nt*32 + laneN4;
        #pragma unroll
        for (int r = 0; r < 16; ++r) {
            const int n = nb + (r & 3) + ((r >> 2) << 3);
            float v = acc[r];
            bool g = v > v1;
            v2 = fmaxf(v2, fminf(v1, v));
            v1 = fmaxf(v1, v);
            i1 = g ? n : i1;
        }
        __syncthreads();   // next tile staged + all reads of kbuf[bf] done
    }

    // ---- merge lane^32 halves (n-rows split by +4*hi)
    float o1 = __shfl_xor(v1, 32), o2 = __shfl_xor(v2, 32);
    int oi = __shfl_xor(i1, 32);
    bool sw = (o1 > v1) || (o1 == v1 && oi < i1);
    const float V1 = sw ? o1 : v1;
    int idx = sw ? oi : i1;
    const float V2 = fmaxf(fminf(v1, o1), fmaxf(v2, o2));

    // ---- exact fp32 full repair for near-ties (one ballot bit per l-row)
    unsigned long long mf = __ballot(V1 - V2 < TAU) & 0xffffffffull;
    float* qb = qbuf[wid];
    while (mf) {
        int src = (int)__builtin_ctzll(mf); mf &= mf - 1;
        int rl = l0w + src;
        qb[lane]      = SCALE * xb[(size_t)lane*L_ + rl];
        qb[lane + 64] = SCALE * xb[(size_t)(lane+64)*L_ + rl];
        __builtin_amdgcn_wave_barrier();
        asm volatile("s_waitcnt lgkmcnt(0)" ::: "memory");
        float accs[8];
        #pragma unroll
        for (int u = 0; u < 8; ++u) accs[u] = 0.f;
        const float* kr = K32 + ((size_t)(h*NC_ + lane))*D_;
        for (int d4 = 0; d4 < 32; ++d4) {
            float qd0 = qb[d4*4+0], qd1 = qb[d4*4+1], qd2 = qb[d4*4+2], qd3 = qb[d4*4+3];
            #pragma unroll
            for (int u = 0; u < 8; ++u) {
                f32x4 kk = *(const f32x4*)(kr + (size_t)u*64*D_ + d4*4);
                accs[u] = fmaf(qd0, kk[0], accs[u]);
                accs[u] = fmaf(qd1, kk[1], accs[u]);
                accs[u] = fmaf(qd2, kk[2], accs[u]);
                accs[u] = fmaf(qd3, kk[3], accs[u]);
            }
        }
        float bv = -INFINITY; int bn = 0;
        #pragma unroll
        for (int u = 0; u < 8; ++u) {
            if (accs[u] > bv) { bv = accs[u]; bn = lane + (u << 6); }
        }
        #pragma unroll
        for (int m = 1; m < 64; m <<= 1) {
            float ov = __shfl_xor(bv, m);
            int on = __shfl_xor(bn, m);
            if (ov > bv || (ov == bv && on < bn)) { bv = ov; bn = on; }
        }
        if (lane == src) idx = bn;
        __builtin_amdgcn_wave_barrier();
    }
    idx = __shfl(idx, colL);   // broadcast repaired idx to the hi-half lane

    // ---- outputs: idx (as float, lanes 0-31) + fused V gather (d split by hi)
    const int myl = l0w + colL;
    if (!hi) idxf[((size_t)(b*H_ + h))*L_ + myl] = (float)idx;
    const f32x4* vrow = (const f32x4*)(V + ((size_t)(h*NC_ + idx))*D_);
    float* ob = out + ((size_t)(b*1024 + h*128 + hi*64))*L_ + myl;
    #pragma unroll
    for (int p = 0; p < 16; ++p) {
        f32x4 vv = vrow[hi*16 + p];
        ob[(size_t)(p*4+0)*L_] = vv[0];
        ob[(size_t)(p*4+1)*L_] = vv[1];
        ob[(size_t)(p*4+2)*L_] = vv[2];
        ob[(size_t)(p*4+3)*L_] = vv[3];
    }
}

extern "C" void kernel_launch(void* const* d_in, const int* in_sizes, int n_in,
                              void* d_out, int out_size, void* d_ws, size_t ws_size,
                              hipStream_t stream)
{
    const float* x     = (const float*)d_in[0];
    const float* codes = (const float*)d_in[1];
    const float* Wk    = (const float*)d_in[2];
    const float* Wv    = (const float*)d_in[3];

    float* out  = (float*)d_out;
    float* idxf = out + (size_t)B_ * H_ * D_ * L_;

    _Float16* K16f = (_Float16*)d_ws;                        // 1 MB
    float*    K32  = (float*)((char*)d_ws + (1u << 20));     // 2 MB
    float*    Vf   = (float*)((char*)d_ws + (3u << 20));     // 2 MB

    kv_pre<<<dim3(64, 8), 256, 0, stream>>>(codes, Wk, Wv, K16f, K32, Vf);
    attn_main<<<dim3(1024), 256, 0, stream>>>(x, K16f, K32, Vf, out, idxf);
}